// Round 1
// baseline (345.078 us; speedup 1.0000x reference)
//
#include <hip/hip_runtime.h>
#include <stdint.h>

// SmallMLP: x[65536,784] @ tern(w1[320,784])^T + b1 -> tern -> @ tern(w2[10,320])^T + b2 -> log_softmax
// R4: latency-bound fix. m97-pattern pipeline:
//   - B staged via global_load_lds (width 16) double-buffer; loads issued AFTER the barrier
//     so they stay in flight across the whole next compute phase (1 barrier/chunk).
//   - A (x) loaded directly global -> register fragments (16x16x32 A frag = 8 contiguous
//     floats per lane); hi/lo bf16 split via v_cvt_pk_bf16_f32 (no LDS roundtrip, no manual RNE).
//   - 512-thread blocks (8 waves, 32x160 wave tile, acc[2][10]) + LDS 52.5 KB -> 16 waves/CU.

#define TERN_TH 0.001f

using bf16x8 = __attribute__((ext_vector_type(8))) short;   // 8 bf16 = 4 VGPR
using f32x4  = __attribute__((ext_vector_type(4))) float;   // 4 fp32 acc

typedef unsigned int u32;
#define AS1 __attribute__((address_space(1)))
#define AS3 __attribute__((address_space(3)))

__device__ __forceinline__ unsigned short f2bf(float f) {
    unsigned u = __float_as_uint(f);
    u = (u + 0x7FFFu + ((u >> 16) & 1u)) >> 16;   // RNE
    return (unsigned short)u;
}
__device__ __forceinline__ float ternf(float w) {
    return (w > TERN_TH) ? 1.0f : ((w < -TERN_TH) ? -1.0f : 0.0f);
}
// packed bf16 convert: [15:0]=bf16(a), [31:16]=bf16(b)
__device__ __forceinline__ unsigned cvt_pk_bf16(float a, float b) {
    unsigned r;
    asm("v_cvt_pk_bf16_f32 %0, %1, %2" : "=v"(r) : "v"(a), "v"(b));
    return r;
}

// ---------------- prep: ternarize w1 -> bf16, tiled [25 chunks][320 rows][32 k]
#define Q1T_ELEMS (25 * 320 * 32)
__global__ void prep_q1(const float* __restrict__ w1, unsigned short* __restrict__ q1t) {
    int idx = blockIdx.x * 256 + threadIdx.x;
    if (idx >= Q1T_ELEMS) return;
    int c  = idx / (320 * 32);
    int r  = idx % (320 * 32);
    int j  = r / 32;
    int kk = r % 32;
    int k  = c * 32 + kk;
    float v = (k < 784) ? ternf(w1[j * 784 + k]) : 0.0f;
    q1t[idx] = f2bf(v);
}

// ---------------- LDS layout (bytes)
// main loop: B double buffer [320][32] bf16 = 20480 each
#define LDS_B0 0
#define LDS_B1 20480                 // -> 40960
// epilogue (overlaps B, dead by then): H [64][328] bf16 = 41984; Q2 [16][328] bf16 = 10496
#define LDS_H  0
#define LDS_Q2 41984
#define LDS_TOTAL 52480

#define BCHUNK_BYTES 20480           // 320*32*2 = 20 gll calls of 1024 B

__global__ __launch_bounds__(512, 2) void mlp_main(
    const float* __restrict__ x, const unsigned short* __restrict__ q1t,
    const float* __restrict__ b1, const float* __restrict__ w2,
    const float* __restrict__ b2, float* __restrict__ out) {

    __shared__ __attribute__((aligned(16))) unsigned char smem[LDS_TOTAL];
    unsigned short* sm16 = (unsigned short*)smem;

    const int tid  = threadIdx.x;
    const int lane = tid & 63;
    const int wave = tid >> 6;     // 8 waves
    const int quad = lane >> 4;
    const int l15  = lane & 15;
    const int wm   = wave >> 1;    // 0..3: 32-row group
    const int wn   = wave & 1;     // 0..1: 160-col half
    const int blk  = blockIdx.x;   // 512 blocks * 128 rows

    f32x4 acc[2][10];
#pragma unroll
    for (int mt = 0; mt < 2; ++mt)
#pragma unroll
        for (int nt = 0; nt < 10; ++nt) {
            f32x4 z = {0.f, 0.f, 0.f, 0.f};
            acc[mt][nt] = z;
        }

    // A fragment source: lane holds row (wm*32 + mt*16 + l15), k = quad*8..+8
    const float* xrow = x + (size_t)(blk * 128 + wm * 32 + l15) * 784;

    float4 ra[2][2];               // raw x for next chunk (32 B/lane per mt)
    bf16x8 ahi[2], alo[2];         // current chunk's A fragments (hi/lo split)

    // ---- B chunk stage: 20 calls of 64 lanes x 16 B, spread over 8 waves (3/3/3/3/2/2/2/2)
    auto stageB = [&](int c, int bufoff) {
        const unsigned char* src = (const unsigned char*)q1t + (size_t)c * BCHUNK_BYTES;
#pragma unroll
        for (int i = 0; i < 3; ++i) {
            int call = wave + i * 8;
            if (call < 20) {
                __builtin_amdgcn_global_load_lds(
                    (const AS1 u32*)(src + call * 1024 + lane * 16),
                    (AS3 u32*)(smem + bufoff + call * 1024),
                    16, 0, 0);
            }
        }
    };
    // ---- A raw load for chunk cc (K tail: cc==24 covers k 768..799, quads 2,3 -> zero)
    auto loadAc = [&](int cc) {
#pragma unroll
        for (int mt = 0; mt < 2; ++mt) {
            const float4* p = (const float4*)(xrow + (size_t)mt * 16 * 784 + cc * 32 + quad * 8);
            if (cc == 24 && quad >= 2) {
                float4 z; z.x = z.y = z.z = z.w = 0.f;
                ra[mt][0] = z; ra[mt][1] = z;
            } else {
                ra[mt][0] = p[0]; ra[mt][1] = p[1];
            }
        }
    };
    // ---- hi/lo bf16 split in registers (hw packed cvt; residual exact in fp32)
    auto convA = [&]() {
#pragma unroll
        for (int mt = 0; mt < 2; ++mt) {
            float v[8] = {ra[mt][0].x, ra[mt][0].y, ra[mt][0].z, ra[mt][0].w,
                          ra[mt][1].x, ra[mt][1].y, ra[mt][1].z, ra[mt][1].w};
            union { unsigned w[4]; bf16x8 b; } uh, ul;
#pragma unroll
            for (int i = 0; i < 4; ++i) {
                unsigned hp = cvt_pk_bf16(v[2 * i], v[2 * i + 1]);
                float h0 = __uint_as_float(hp << 16);
                float h1 = __uint_as_float(hp & 0xffff0000u);
                uh.w[i] = hp;
                ul.w[i] = cvt_pk_bf16(v[2 * i] - h0, v[2 * i + 1] - h1);
            }
            ahi[mt] = uh.b; alo[mt] = ul.b;
        }
    };

    // ---- prologue
    stageB(0, LDS_B0);
    loadAc(0);
    convA();                       // frags for c=0 (compiler auto-waits the raw loads)
    __syncthreads();               // drains gll(0) for all waves
    stageB(1, LDS_B1);
    loadAc(1);

    const int bqo = wn * 10240 + l15 * 64 + quad * 16;   // B frag: col*64 + quad*16

    for (int c = 0; c < 25; ++c) {
        const int bo = (c & 1) ? LDS_B1 : LDS_B0;
        // ---- compute chunk c (B from LDS, A from regs); gll(c+1)/A(c+1) in flight
#pragma unroll
        for (int nt = 0; nt < 10; ++nt) {
            bf16x8 bq = *(const bf16x8*)(smem + bo + bqo + nt * 1024);
#pragma unroll
            for (int mt = 0; mt < 2; ++mt) {
                acc[mt][nt] = __builtin_amdgcn_mfma_f32_16x16x32_bf16(ahi[mt], bq, acc[mt][nt], 0, 0, 0);
                acc[mt][nt] = __builtin_amdgcn_mfma_f32_16x16x32_bf16(alo[mt], bq, acc[mt][nt], 0, 0, 0);
            }
        }
        if (c < 24) {
            convA();               // frags for c+1 (raw loads are a full compute-phase old)
            __syncthreads();       // compiler's vmcnt(0) drain lands here -> buf(c+1) valid,
                                   // and all waves are done reading buf(c&1)
            if (c < 23) {
                stageB(c + 2, bo); // refill the buffer just consumed; flies across next compute
                loadAc(c + 2);
            }
        }
    }

    // ---------------- fused epilogue (layer 2 + log_softmax)
    __syncthreads();
    // stage q2: tern(w2) -> bf16 [16][328], rows 10..15 and cols 320..327 zero
    for (int idx = tid; idx < 16 * 328; idx += 512) {
        int o = idx / 328, j = idx % 328;
        float v = (o < 10 && j < 320) ? ternf(w2[o * 320 + j]) : 0.0f;
        sm16[(LDS_Q2 >> 1) + idx] = f2bf(v);
    }
    float b1v[10];
#pragma unroll
    for (int nt = 0; nt < 10; ++nt) b1v[nt] = b1[wn * 160 + nt * 16 + l15];
    float b2v = (l15 < 10) ? b2[l15] : 0.0f;

    for (int pass = 0; pass < 2; ++pass) {
        __syncthreads();
        // waves owning this 64-row half write ternarized h (bf16) to LDS
        if ((wm >> 1) == pass) {
#pragma unroll
            for (int mt = 0; mt < 2; ++mt)
#pragma unroll
                for (int nt = 0; nt < 10; ++nt)
#pragma unroll
                    for (int i = 0; i < 4; ++i) {
                        float hv = acc[mt][nt][i] + b1v[nt];
                        int row = (wm & 1) * 32 + mt * 16 + quad * 4 + i;   // C layout: col=l15, row=quad*4+reg
                        int col = wn * 160 + nt * 16 + l15;
                        sm16[(LDS_H >> 1) + row * 328 + col] = f2bf(ternf(hv));
                    }
        }
        __syncthreads();
        // layer 2: waves 0..3 compute 16 rows x 16 cols (10 valid), K=320
        if (wave < 4) {
            f32x4 acc2 = {0.f, 0.f, 0.f, 0.f};
#pragma unroll
            for (int kc = 0; kc < 10; ++kc) {
                bf16x8 a = *(const bf16x8*)(smem + LDS_H + (wave * 16 + l15) * 656 + kc * 64 + quad * 16);
                bf16x8 b = *(const bf16x8*)(smem + LDS_Q2 + l15 * 656 + kc * 64 + quad * 16);
                acc2 = __builtin_amdgcn_mfma_f32_16x16x32_bf16(a, b, acc2, 0, 0, 0);
            }
            // log_softmax across the 16 lanes holding one row (cols), 10 valid
#pragma unroll
            for (int i = 0; i < 4; ++i) {
                float l  = acc2[i] + b2v;
                float lm = (l15 < 10) ? l : -3.4e38f;
#pragma unroll
                for (int s = 8; s >= 1; s >>= 1) lm = fmaxf(lm, __shfl_xor(lm, s, 64));
                float e  = (l15 < 10) ? expf(l - lm) : 0.0f;
                float ss = e;
#pragma unroll
                for (int s = 8; s >= 1; s >>= 1) ss += __shfl_xor(ss, s, 64);
                float ov = (l - lm) - logf(ss);
                if (l15 < 10) {
                    int grow = blk * 128 + pass * 64 + wave * 16 + quad * 4 + i;
                    out[(size_t)grow * 10 + l15] = ov;
                }
            }
        }
    }
}

extern "C" void kernel_launch(void* const* d_in, const int* in_sizes, int n_in,
                              void* d_out, int out_size, void* d_ws, size_t ws_size,
                              hipStream_t stream) {
    const float* x  = (const float*)d_in[0];
    const float* w1 = (const float*)d_in[1];
    const float* b1 = (const float*)d_in[2];
    const float* w2 = (const float*)d_in[3];
    const float* b2 = (const float*)d_in[4];
    unsigned short* q1t = (unsigned short*)d_ws;   // 512000 B

    prep_q1<<<(Q1T_ELEMS + 255) / 256, 256, 0, stream>>>(w1, q1t);
    mlp_main<<<512, 512, 0, stream>>>(x, q1t, b1, w2, b2, (float*)d_out);
}